// Round 5
// baseline (525.324 us; speedup 1.0000x reference)
//
#include <hip/hip_runtime.h>
#include <hip/hip_bf16.h>

typedef __attribute__((ext_vector_type(8))) short short8;
typedef __attribute__((ext_vector_type(4))) float f32x4;

#define EPSV 1e-5f

__device__ __forceinline__ float bf2f(ushort u){
  union { uint i; float f; } x; x.i = ((uint)u) << 16; return x.f;
}
__device__ __forceinline__ ushort f2bf(float f){
  union { float f; uint i; } x; x.f = f;
  uint r = (x.i + 0x7FFFu + ((x.i >> 16) & 1u)) >> 16;
  return (ushort)r;
}

// ---------------- init: zero stats, max accumulators, row 0 of x1 ----------------
__global__ void init_kernel(ushort* x1, float* stats, int* maxbuf){
  int i = blockIdx.x * 256 + threadIdx.x;   // 32768 threads
  if (i < 384)  stats[i] = 0.f;
  if (i < 8192) maxbuf[i] = 0;
  if (i < 32768){ int b = i >> 9, c = i & 511; x1[(size_t)b*1025*512 + c] = 0; }
}

// ---------------- zero node-0 rows of x2 (AFTER aug is dead: aug aliases x2) ----------------
__global__ void zero2_kernel(ushort* x2){
  int i = blockIdx.x * 256 + threadIdx.x;   // 16384 threads
  int b = i >> 8, c = i & 255;
  x2[(size_t)b*1025*256 + c] = 0;
}

// ---------------- q_conv: 4 stacked linears, no activations ----------------
__global__ void qconv_kernel(const float* __restrict__ qv,
    const float* __restrict__ W1, const float* __restrict__ b1,
    const float* __restrict__ W2, const float* __restrict__ b2,
    const float* __restrict__ W3, const float* __restrict__ b3,
    const float* __restrict__ W4, const float* __restrict__ b4,
    float* __restrict__ qout){
  __shared__ float v0[96], h1[64], h2[128], h3[64];
  int b = blockIdx.x, t = threadIdx.x;
  if (t < 95) v0[t] = qv[b*95 + t];
  __syncthreads();
  if (t < 64){ float s = b1[t]; for (int i=0;i<95;i++)  s += v0[i]*W1[i*64 + t];  h1[t]=s; }
  __syncthreads();
  if (t < 128){ float s = b2[t]; for (int i=0;i<64;i++)  s += h1[i]*W2[i*128 + t]; h2[t]=s; }
  __syncthreads();
  if (t < 64){ float s = b3[t]; for (int i=0;i<128;i++) s += h2[i]*W3[i*64 + t];  h3[t]=s; }
  __syncthreads();
  if (t < 32){ float s = b4[t]; for (int i=0;i<64;i++)  s += h3[i]*W4[i*32 + t];  qout[b*32 + t]=s; }
}

// ---------------- build augmented input (B,1025,128) bf16 ----------------
__global__ void aug_kernel(const float* __restrict__ trees, const float* __restrict__ q,
                           ushort* __restrict__ aug){
  int n = blockIdx.x;            // 0..1024
  int b = blockIdx.y;            // 0..63
  int c = threadIdx.x;           // 0..127
  float v = (c < 96) ? trees[((size_t)b*1025 + n)*96 + c] : q[b*32 + (c - 96)];
  aug[(((size_t)b*1025 + n) << 7) + c] = f2bf(v);
}

// ---------------- weight transpose: Wt[o][kp*C+c] = Wc[o][c][kp], bf16 ----------------
__global__ void prepw_kernel(const float* __restrict__ wc, ushort* __restrict__ wt,
                             int O, int C){
  int i = blockIdx.x * 256 + threadIdx.x;
  int total = O * 3 * C;
  if (i >= total) return;
  int o  = i / (3*C);
  int K  = i - o*3*C;
  int kp = K / C;
  int c  = K - kp*C;
  wt[i] = f2bf(wc[(o*C + c)*3 + kp]);
}

// ---------------- gathered conv as MFMA GEMM ----------------
// 128x128 tile, BK=64 (2 sub-steps), reg-staged double-buffer (issue-early /
// write-late), XOR-swizzled per-plane LDS [buf][plane][128][32]:
//   phys 16B-chunk = log_chunk ^ ((row>>1)&3)  on both ds_write and ds_read
//   -> bank-balanced writes (2-way max) and conflict-free b128 frag reads.
template<int CIN, int GY, bool DO_MAX>
__global__ __launch_bounds__(256) void conv_kernel(
    const ushort* __restrict__ xin, const ushort* __restrict__ wt,
    const float* __restrict__ bias, const int* __restrict__ idxes,
    ushort* __restrict__ xout, float* __restrict__ stats, int* __restrict__ maxbuf){
  constexpr int K3   = 3 * CIN;
  constexpr int NT   = K3 / 64;          // K-chunks of 64
  constexpr int COUT = GY * 128;
  constexpr int NWG  = 8 * GY * 64;

  // XCD swizzle: physical XCD of block = bid%8; give each XCD a contiguous
  // wu range -> same-batch blocks share one XCD's L2 (verified FETCH 97->75MB).
  const int bid  = blockIdx.x;
  const int wu   = (bid & 7) * (NWG >> 3) + (bid >> 3);
  const int m0   = (wu & 7) * 128;
  const int rest = wu >> 3;
  const int o0   = (rest % GY) * 128;
  const int b    = rest / GY;

  const int t = threadIdx.x;
  const int lane = t & 63, wid = t >> 6;
  const int WM = (wid & 1) * 64, WO = (wid >> 1) * 64;
  const int fr = lane & 15, fg = lane >> 4;
  const int fc = (fg ^ ((fr >> 1) & 3)) * 8;   // swizzled read column (ushorts)

  __shared__ __align__(16) union {
    struct { ushort A[2][2][128][32]; ushort B[2][2][128][32]; } s;   // 64 KB
    ushort stage[128][132];
  } sh;
  __shared__ int idx_s[384];

  for (int i = t; i < 384; i += 256) idx_s[i] = idxes[b*3072 + m0*3 + i];
  __syncthreads();

  // staging: thread t owns row r=t>>1, k-plane p=t&1 (32 elems = 4x16B chunks)
  const int r = t >> 1, p = t & 1, sx = (r >> 1) & 3;
  const int n0 = idx_s[r*3 + 0], n1 = idx_s[r*3 + 1], n2 = idx_s[r*3 + 2];
  const ushort* xb = xin + (size_t)b * 1025 * CIN;
  const ushort* wrow = wt + (size_t)(o0 + r) * K3 + p*32;

  uint4 ra[4], rb[4];
  auto GLOAD = [&](int ch){
    const int kb = ch * 64;
    const int kp = kb / CIN;
    const int c0 = kb - kp * CIN + p*32;
    const int node = (kp == 0) ? n0 : (kp == 1) ? n1 : n2;
    const ushort* sa = xb + (size_t)node * CIN + c0;
    #pragma unroll
    for (int l = 0; l < 4; ++l) ra[l] = *reinterpret_cast<const uint4*>(sa + l*8);
    const ushort* sb = wrow + kb;
    #pragma unroll
    for (int l = 0; l < 4; ++l) rb[l] = *reinterpret_cast<const uint4*>(sb + l*8);
  };
  auto DSW = [&](int bf){
    #pragma unroll
    for (int l = 0; l < 4; ++l)
      *reinterpret_cast<uint4*>(&sh.s.A[bf][p][r][(l ^ sx)*8]) = ra[l];
    #pragma unroll
    for (int l = 0; l < 4; ++l)
      *reinterpret_cast<uint4*>(&sh.s.B[bf][p][r][(l ^ sx)*8]) = rb[l];
  };

  f32x4 acc[4][4] = {};

  GLOAD(0);
  DSW(0);
  __syncthreads();

  for (int ch = 0; ch < NT; ++ch){
    if (ch + 1 < NT) GLOAD(ch + 1);      // issue next chunk early (T14)
    const int cur = ch & 1;
    #pragma unroll
    for (int sub = 0; sub < 2; ++sub){
      short8 af[4], bf4[4];
      #pragma unroll
      for (int i = 0; i < 4; ++i){
        af[i]  = *reinterpret_cast<const short8*>(&sh.s.A[cur][sub][WM + i*16 + fr][fc]);
        bf4[i] = *reinterpret_cast<const short8*>(&sh.s.B[cur][sub][WO + i*16 + fr][fc]);
      }
      __builtin_amdgcn_s_setprio(1);
      #pragma unroll
      for (int mf = 0; mf < 4; ++mf)
        #pragma unroll
        for (int nf = 0; nf < 4; ++nf)
          acc[mf][nf] = __builtin_amdgcn_mfma_f32_16x16x32_bf16(af[mf], bf4[nf], acc[mf][nf], 0, 0, 0);
      __builtin_amdgcn_s_setprio(0);
    }
    if (ch + 1 < NT){
      DSW(cur ^ 1);                      // wait-at-write; hidden by the 32 MFMAs
      __syncthreads();
    }
  }

  // ---- epilogue: bias, stats, optional max, optional store ----
  float bsv[4];
  #pragma unroll
  for (int nf = 0; nf < 4; ++nf) bsv[nf] = bias[o0 + WO + nf*16 + fr];
  float lsum = 0.f, lsq = 0.f;
  float cmax[4] = { -1e30f, -1e30f, -1e30f, -1e30f };
  #pragma unroll
  for (int mf = 0; mf < 4; ++mf)
    #pragma unroll
    for (int nf = 0; nf < 4; ++nf)
      #pragma unroll
      for (int i = 0; i < 4; ++i){
        float v = acc[mf][nf][i] + bsv[nf];
        lsum += v; lsq += v*v;
        if (DO_MAX) cmax[nf] = fmaxf(cmax[nf], v);
        else acc[mf][nf][i] = v;
      }
  #pragma unroll
  for (int off = 1; off < 64; off <<= 1){
    lsum += __shfl_xor(lsum, off);
    lsq  += __shfl_xor(lsq,  off);
  }
  if (lane == 0){
    atomicAdd(&stats[b],      lsum);
    atomicAdd(&stats[64 + b], lsq);
  }
  if (DO_MAX){
    #pragma unroll
    for (int nf = 0; nf < 4; ++nf){
      float v = cmax[nf];
      v = fmaxf(v, __shfl_xor(v, 16));
      v = fmaxf(v, __shfl_xor(v, 32));
      if (lane < 16)
        atomicMax(&maxbuf[b*COUT + o0 + WO + nf*16 + fr], __float_as_int(v));
    }
  } else {
    __syncthreads();   // all waves done with K-buffers; reuse as staging
    #pragma unroll
    for (int mf = 0; mf < 4; ++mf)
      #pragma unroll
      for (int nf = 0; nf < 4; ++nf)
        #pragma unroll
        for (int i = 0; i < 4; ++i)
          sh.stage[WM + mf*16 + fg*4 + i][WO + nf*16 + fr] = f2bf(acc[mf][nf][i]);
    __syncthreads();
    #pragma unroll
    for (int it = 0; it < 16; ++it){
      int row = it*8 + (t >> 5);
      int col = (t & 31) * 4;
      uint2 v = *reinterpret_cast<const uint2*>(&sh.stage[row][col]);
      *reinterpret_cast<uint2*>(xout + ((size_t)(b*1025 + 1 + m0 + row))*COUT + o0 + col) = v;
    }
  }
}

// ---------------- in-place TreeLayerNorm + leaky_relu, bf16x8 vectorized ----------------
__global__ void norm_kernel(ushort* __restrict__ x, const float* __restrict__ st,
                            float cnt, int nvec_per_b){
  int b = blockIdx.y;
  int j = blockIdx.x * 256 + threadIdx.x;
  if (j >= nvec_per_b) return;
  float sum = st[b], sq = st[64 + b];
  float mean = sum / cnt;
  float var  = fmaxf((sq - sum*sum/cnt) / (cnt - 1.f), 0.f);
  float rs   = 1.f / (sqrtf(var) + EPSV);
  ushort* p = x + ((size_t)b * nvec_per_b + j) * 8;
  union { uint4 v; ushort u[8]; } d;
  d.v = *reinterpret_cast<const uint4*>(p);
  #pragma unroll
  for (int k = 0; k < 8; ++k){
    float f = bf2f(d.u[k]);
    f = (f - mean) * rs;
    f = (f >= 0.f) ? f : 0.01f * f;
    d.u[k] = f2bf(f);
  }
  *reinterpret_cast<uint4*>(p) = d.v;
}

// ---------------- final: normalize the per-channel max ----------------
__global__ void final_kernel(const int* __restrict__ maxbuf, const float* __restrict__ st,
                             float* __restrict__ out){
  int i = blockIdx.x * 256 + threadIdx.x;   // 8192
  int b = i >> 7;
  const float cnt = 131200.f;
  float sum = st[b], sq = st[64 + b];
  float mean = sum / cnt;
  float var  = fmaxf((sq - sum*sum/cnt) / (cnt - 1.f), 0.f);
  float rs   = 1.f / (sqrtf(var) + EPSV);
  out[i] = (__int_as_float(maxbuf[i]) - mean) * rs;
}

// ---------------- workspace layout ----------------
static constexpr size_t SZ_X1  = (size_t)64*1025*512*2;   // 67,174,400
static constexpr size_t SZ_X2  = (size_t)64*1025*256*2;   // 33,587,200
static constexpr size_t OFF_X1 = 0;
static constexpr size_t OFF_X2 = OFF_X1 + SZ_X1;
static constexpr size_t OFF_AUG = OFF_X2;                 // alias: aug dead after conv1
static constexpr size_t OFF_WT1 = OFF_X2 + SZ_X2;
static constexpr size_t OFF_WT2 = OFF_WT1 + (size_t)512*384*2;
static constexpr size_t OFF_WT3 = OFF_WT2 + (size_t)256*1536*2;
static constexpr size_t OFF_Q   = OFF_WT3 + (size_t)128*768*2;
static constexpr size_t OFF_ST  = OFF_Q + (size_t)64*32*4;
static constexpr size_t OFF_MAX = OFF_ST + (size_t)384*4;

extern "C" void kernel_launch(void* const* d_in, const int* in_sizes, int n_in,
                              void* d_out, int out_size, void* d_ws, size_t ws_size,
                              hipStream_t stream){
  const float* q_vecs = (const float*)d_in[0];
  const float* trees  = (const float*)d_in[1];
  const int*   idxes  = (const int*)  d_in[2];
  const float* Wq1 = (const float*)d_in[3];  const float* bq1 = (const float*)d_in[4];
  const float* Wq2 = (const float*)d_in[5];  const float* bq2 = (const float*)d_in[6];
  const float* Wq3 = (const float*)d_in[7];  const float* bq3 = (const float*)d_in[8];
  const float* Wq4 = (const float*)d_in[9];  const float* bq4 = (const float*)d_in[10];
  const float* Wc1 = (const float*)d_in[11]; const float* bc1 = (const float*)d_in[12];
  const float* Wc2 = (const float*)d_in[13]; const float* bc2 = (const float*)d_in[14];
  const float* Wc3 = (const float*)d_in[15]; const float* bc3 = (const float*)d_in[16];
  float* out = (float*)d_out;
  char* ws = (char*)d_ws;

  ushort* x1    = (ushort*)(ws + OFF_X1);
  ushort* x2    = (ushort*)(ws + OFF_X2);
  ushort* aug   = (ushort*)(ws + OFF_AUG);
  ushort* wt1   = (ushort*)(ws + OFF_WT1);
  ushort* wt2   = (ushort*)(ws + OFF_WT2);
  ushort* wt3   = (ushort*)(ws + OFF_WT3);
  float*  qbuf  = (float*) (ws + OFF_Q);
  float*  stats = (float*) (ws + OFF_ST);
  int*    maxb  = (int*)   (ws + OFF_MAX);

  init_kernel<<<128, 256, 0, stream>>>(x1, stats, maxb);
  qconv_kernel<<<64, 128, 0, stream>>>(q_vecs, Wq1,bq1, Wq2,bq2, Wq3,bq3, Wq4,bq4, qbuf);
  aug_kernel<<<dim3(1025, 64), 128, 0, stream>>>(trees, qbuf, aug);
  prepw_kernel<<<(512*384 + 255)/256, 256, 0, stream>>>(Wc1, wt1, 512, 128);
  prepw_kernel<<<(256*1536 + 255)/256, 256, 0, stream>>>(Wc2, wt2, 256, 512);
  prepw_kernel<<<(128*768 + 255)/256, 256, 0, stream>>>(Wc3, wt3, 128, 256);

  conv_kernel<128, 4, false><<<2048, 256, 0, stream>>>(aug, wt1, bc1, idxes, x1, stats +   0, nullptr);
  zero2_kernel<<<64, 256, 0, stream>>>(x2);   // aug (aliased with x2) is dead now
  norm_kernel<<<dim3((65600 + 255)/256, 64), 256, 0, stream>>>(x1, stats +   0, 524800.f, 65600);
  conv_kernel<512, 2, false><<<1024, 256, 0, stream>>>(x1,  wt2, bc2, idxes, x2, stats + 128, nullptr);
  norm_kernel<<<dim3((32800 + 255)/256, 64), 256, 0, stream>>>(x2, stats + 128, 262400.f, 32800);
  conv_kernel<256, 1, true ><<<512, 256, 0, stream>>>(x2,  wt3, bc3, idxes, nullptr, stats + 256, maxb);
  final_kernel<<<32, 256, 0, stream>>>(maxb, stats + 256, out);
}

// Round 6
// 276.371 us; speedup vs baseline: 1.9008x; 1.9008x over previous
//
#include <hip/hip_runtime.h>
#include <hip/hip_bf16.h>

typedef __attribute__((ext_vector_type(8))) short short8;
typedef __attribute__((ext_vector_type(4))) float f32x4;

#define EPSV 1e-5f

__device__ __forceinline__ float bf2f(ushort u){
  union { uint i; float f; } x; x.i = ((uint)u) << 16; return x.f;
}
__device__ __forceinline__ ushort f2bf(float f){
  union { float f; uint i; } x; x.f = f;
  uint r = (x.i + 0x7FFFu + ((x.i >> 16) & 1u)) >> 16;
  return (ushort)r;
}

// ---------------- init: zero stats, max accumulators, row 0 of x1 ----------------
__global__ void init_kernel(ushort* x1, float* stats, int* maxbuf){
  int i = blockIdx.x * 256 + threadIdx.x;   // 32768 threads
  if (i < 384)  stats[i] = 0.f;
  if (i < 8192) maxbuf[i] = 0;
  if (i < 32768){ int b = i >> 9, c = i & 511; x1[(size_t)b*1025*512 + c] = 0; }
}

// ---------------- zero node-0 rows of x2 (AFTER aug is dead: aug aliases x2) ----------------
__global__ void zero2_kernel(ushort* x2){
  int i = blockIdx.x * 256 + threadIdx.x;   // 16384 threads
  int b = i >> 8, c = i & 255;
  x2[(size_t)b*1025*256 + c] = 0;
}

// ---------------- q_conv: 4 stacked linears, no activations ----------------
__global__ void qconv_kernel(const float* __restrict__ qv,
    const float* __restrict__ W1, const float* __restrict__ b1,
    const float* __restrict__ W2, const float* __restrict__ b2,
    const float* __restrict__ W3, const float* __restrict__ b3,
    const float* __restrict__ W4, const float* __restrict__ b4,
    float* __restrict__ qout){
  __shared__ float v0[96], h1[64], h2[128], h3[64];
  int b = blockIdx.x, t = threadIdx.x;
  if (t < 95) v0[t] = qv[b*95 + t];
  __syncthreads();
  if (t < 64){ float s = b1[t]; for (int i=0;i<95;i++)  s += v0[i]*W1[i*64 + t];  h1[t]=s; }
  __syncthreads();
  if (t < 128){ float s = b2[t]; for (int i=0;i<64;i++)  s += h1[i]*W2[i*128 + t]; h2[t]=s; }
  __syncthreads();
  if (t < 64){ float s = b3[t]; for (int i=0;i<128;i++) s += h2[i]*W3[i*64 + t];  h3[t]=s; }
  __syncthreads();
  if (t < 32){ float s = b4[t]; for (int i=0;i<64;i++)  s += h3[i]*W4[i*32 + t];  qout[b*32 + t]=s; }
}

// ---------------- build augmented input (B,1025,128) bf16 ----------------
__global__ void aug_kernel(const float* __restrict__ trees, const float* __restrict__ q,
                           ushort* __restrict__ aug){
  int n = blockIdx.x;            // 0..1024
  int b = blockIdx.y;            // 0..63
  int c = threadIdx.x;           // 0..127
  float v = (c < 96) ? trees[((size_t)b*1025 + n)*96 + c] : q[b*32 + (c - 96)];
  aug[(((size_t)b*1025 + n) << 7) + c] = f2bf(v);
}

// ---------------- weight transpose: Wt[o][kp*C+c] = Wc[o][c][kp], bf16 ----------------
__global__ void prepw_kernel(const float* __restrict__ wc, ushort* __restrict__ wt,
                             int O, int C){
  int i = blockIdx.x * 256 + threadIdx.x;
  int total = O * 3 * C;
  if (i >= total) return;
  int o  = i / (3*C);
  int K  = i - o*3*C;
  int kp = K / C;
  int c  = K - kp*C;
  wt[i] = f2bf(wc[(o*C + c)*3 + kp]);
}

// ---------------- gathered conv as MFMA GEMM ----------------
// 128x128 tile, BK=32, reg-staged double-buffer (issue-early / write-late).
// LDS: linear [buf][128][32] per operand; 16B-chunk swizzle:
//   phys_chunk = log_chunk ^ ((row>>1)&3)  on BOTH ds_write and ds_read
//   -> frag reads 2-way max (free), staging writes bank-balanced (minimum cycles).
template<int CIN, int GY, bool DO_MAX>
__global__ __launch_bounds__(256) void conv_kernel(
    const ushort* __restrict__ xin, const ushort* __restrict__ wt,
    const float* __restrict__ bias, const int* __restrict__ idxes,
    ushort* __restrict__ xout, float* __restrict__ stats, int* __restrict__ maxbuf){
  constexpr int K3   = 3 * CIN;
  constexpr int NT   = K3 / 32;          // K-chunks of 32
  constexpr int COUT = GY * 128;
  constexpr int NWG  = 8 * GY * 64;

  // XCD swizzle (verified FETCH 97->75MB): contiguous wu range per XCD ->
  // same-batch blocks share one XCD's L2.
  const int bid  = blockIdx.x;
  const int wu   = (bid & 7) * (NWG >> 3) + (bid >> 3);
  const int m0   = (wu & 7) * 128;
  const int rest = wu >> 3;
  const int o0   = (rest % GY) * 128;
  const int b    = rest / GY;

  const int t = threadIdx.x;
  const int lane = t & 63, wid = t >> 6;
  const int WM = (wid & 1) * 64, WO = (wid >> 1) * 64;
  const int fr = lane & 15, fg = lane >> 4;
  const int fc = (fg ^ ((fr >> 1) & 3)) * 8;   // swizzled read column (ushorts)

  __shared__ __align__(16) union {
    struct { ushort A[2][128][32]; ushort B[2][128][32]; } s;   // 32 KB
    ushort stage[128][132];                                     // 33.8 KB
  } sh;
  __shared__ int idx_s[384];

  for (int i = t; i < 384; i += 256) idx_s[i] = idxes[b*3072 + m0*3 + i];
  __syncthreads();

  // staging: thread t owns row r=t>>1, half h=t&1 (logical chunks 2h, 2h+1)
  const int r = t >> 1, h = t & 1, sx = (r >> 1) & 3;
  const int p0 = ((2*h)     ^ sx) * 8;   // phys ushort offsets
  const int p1 = ((2*h + 1) ^ sx) * 8;
  const int n0 = idx_s[r*3 + 0], n1 = idx_s[r*3 + 1], n2 = idx_s[r*3 + 2];
  const ushort* xb   = xin + (size_t)b * 1025 * CIN;
  const ushort* wrow = wt + (size_t)(o0 + r) * K3 + h*16;

  uint4 ra0, ra1, rb0, rb1;                 // named scalars: no scratch (R5 lesson)
  auto GLOAD = [&](int ch){
    const int k0 = ch * 32;
    const int kp = k0 / CIN;
    const int c0 = k0 - kp * CIN;
    const int node = (kp == 0) ? n0 : (kp == 1) ? n1 : n2;
    const ushort* sa = xb + (size_t)node * CIN + c0 + h*16;
    ra0 = *reinterpret_cast<const uint4*>(sa);
    ra1 = *reinterpret_cast<const uint4*>(sa + 8);
    const ushort* sb = wrow + k0;
    rb0 = *reinterpret_cast<const uint4*>(sb);
    rb1 = *reinterpret_cast<const uint4*>(sb + 8);
  };
  auto DSW = [&](int bf){
    *reinterpret_cast<uint4*>(&sh.s.A[bf][r][p0]) = ra0;
    *reinterpret_cast<uint4*>(&sh.s.A[bf][r][p1]) = ra1;
    *reinterpret_cast<uint4*>(&sh.s.B[bf][r][p0]) = rb0;
    *reinterpret_cast<uint4*>(&sh.s.B[bf][r][p1]) = rb1;
  };

  f32x4 acc[4][4] = {};

  GLOAD(0);
  DSW(0);
  __syncthreads();

  for (int ch = 0; ch < NT; ++ch){
    if (ch + 1 < NT) GLOAD(ch + 1);      // issue next chunk early (T14)
    const int cur = ch & 1;
    short8 af[4], bf4[4];
    #pragma unroll
    for (int i = 0; i < 4; ++i){
      af[i]  = *reinterpret_cast<const short8*>(&sh.s.A[cur][WM + i*16 + fr][fc]);
      bf4[i] = *reinterpret_cast<const short8*>(&sh.s.B[cur][WO + i*16 + fr][fc]);
    }
    __builtin_amdgcn_s_setprio(1);
    #pragma unroll
    for (int mf = 0; mf < 4; ++mf)
      #pragma unroll
      for (int nf = 0; nf < 4; ++nf)
        acc[mf][nf] = __builtin_amdgcn_mfma_f32_16x16x32_bf16(af[mf], bf4[nf], acc[mf][nf], 0, 0, 0);
    __builtin_amdgcn_s_setprio(0);
    if (ch + 1 < NT){
      DSW(cur ^ 1);                      // wait-at-write; hidden under MFMAs
      __syncthreads();
    }
  }

  // ---- epilogue: bias, stats, optional max, optional store ----
  float bsv[4];
  #pragma unroll
  for (int nf = 0; nf < 4; ++nf) bsv[nf] = bias[o0 + WO + nf*16 + fr];
  float lsum = 0.f, lsq = 0.f;
  float cmax[4] = { -1e30f, -1e30f, -1e30f, -1e30f };
  #pragma unroll
  for (int mf = 0; mf < 4; ++mf)
    #pragma unroll
    for (int nf = 0; nf < 4; ++nf)
      #pragma unroll
      for (int i = 0; i < 4; ++i){
        float v = acc[mf][nf][i] + bsv[nf];
        lsum += v; lsq += v*v;
        if (DO_MAX) cmax[nf] = fmaxf(cmax[nf], v);
        else acc[mf][nf][i] = v;
      }
  #pragma unroll
  for (int off = 1; off < 64; off <<= 1){
    lsum += __shfl_xor(lsum, off);
    lsq  += __shfl_xor(lsq,  off);
  }
  if (lane == 0){
    atomicAdd(&stats[b],      lsum);
    atomicAdd(&stats[64 + b], lsq);
  }
  if (DO_MAX){
    #pragma unroll
    for (int nf = 0; nf < 4; ++nf){
      float v = cmax[nf];
      v = fmaxf(v, __shfl_xor(v, 16));
      v = fmaxf(v, __shfl_xor(v, 32));
      if (lane < 16)
        atomicMax(&maxbuf[b*COUT + o0 + WO + nf*16 + fr], __float_as_int(v));
    }
  } else {
    __syncthreads();   // all waves done with K-buffers; reuse as staging
    #pragma unroll
    for (int mf = 0; mf < 4; ++mf)
      #pragma unroll
      for (int nf = 0; nf < 4; ++nf)
        #pragma unroll
        for (int i = 0; i < 4; ++i)
          sh.stage[WM + mf*16 + fg*4 + i][WO + nf*16 + fr] = f2bf(acc[mf][nf][i]);
    __syncthreads();
    #pragma unroll
    for (int it = 0; it < 16; ++it){
      int row = it*8 + (t >> 5);
      int col = (t & 31) * 4;
      uint2 v = *reinterpret_cast<const uint2*>(&sh.stage[row][col]);
      *reinterpret_cast<uint2*>(xout + ((size_t)(b*1025 + 1 + m0 + row))*COUT + o0 + col) = v;
    }
  }
}

// ---------------- in-place TreeLayerNorm + leaky_relu, bf16x8 vectorized ----------------
__global__ void norm_kernel(ushort* __restrict__ x, const float* __restrict__ st,
                            float cnt, int nvec_per_b){
  int b = blockIdx.y;
  int j = blockIdx.x * 256 + threadIdx.x;
  if (j >= nvec_per_b) return;
  float sum = st[b], sq = st[64 + b];
  float mean = sum / cnt;
  float var  = fmaxf((sq - sum*sum/cnt) / (cnt - 1.f), 0.f);
  float rs   = 1.f / (sqrtf(var) + EPSV);
  ushort* p = x + ((size_t)b * nvec_per_b + j) * 8;
  union { uint4 v; ushort u[8]; } d;
  d.v = *reinterpret_cast<const uint4*>(p);
  #pragma unroll
  for (int k = 0; k < 8; ++k){
    float f = bf2f(d.u[k]);
    f = (f - mean) * rs;
    f = (f >= 0.f) ? f : 0.01f * f;
    d.u[k] = f2bf(f);
  }
  *reinterpret_cast<uint4*>(p) = d.v;
}

// ---------------- final: normalize the per-channel max ----------------
__global__ void final_kernel(const int* __restrict__ maxbuf, const float* __restrict__ st,
                             float* __restrict__ out){
  int i = blockIdx.x * 256 + threadIdx.x;   // 8192
  int b = i >> 7;
  const float cnt = 131200.f;
  float sum = st[b], sq = st[64 + b];
  float mean = sum / cnt;
  float var  = fmaxf((sq - sum*sum/cnt) / (cnt - 1.f), 0.f);
  float rs   = 1.f / (sqrtf(var) + EPSV);
  out[i] = (__int_as_float(maxbuf[i]) - mean) * rs;
}

// ---------------- workspace layout ----------------
static constexpr size_t SZ_X1  = (size_t)64*1025*512*2;   // 67,174,400
static constexpr size_t SZ_X2  = (size_t)64*1025*256*2;   // 33,587,200
static constexpr size_t OFF_X1 = 0;
static constexpr size_t OFF_X2 = OFF_X1 + SZ_X1;
static constexpr size_t OFF_AUG = OFF_X2;                 // alias: aug dead after conv1
static constexpr size_t OFF_WT1 = OFF_X2 + SZ_X2;
static constexpr size_t OFF_WT2 = OFF_WT1 + (size_t)512*384*2;
static constexpr size_t OFF_WT3 = OFF_WT2 + (size_t)256*1536*2;
static constexpr size_t OFF_Q   = OFF_WT3 + (size_t)128*768*2;
static constexpr size_t OFF_ST  = OFF_Q + (size_t)64*32*4;
static constexpr size_t OFF_MAX = OFF_ST + (size_t)384*4;

extern "C" void kernel_launch(void* const* d_in, const int* in_sizes, int n_in,
                              void* d_out, int out_size, void* d_ws, size_t ws_size,
                              hipStream_t stream){
  const float* q_vecs = (const float*)d_in[0];
  const float* trees  = (const float*)d_in[1];
  const int*   idxes  = (const int*)  d_in[2];
  const float* Wq1 = (const float*)d_in[3];  const float* bq1 = (const float*)d_in[4];
  const float* Wq2 = (const float*)d_in[5];  const float* bq2 = (const float*)d_in[6];
  const float* Wq3 = (const float*)d_in[7];  const float* bq3 = (const float*)d_in[8];
  const float* Wq4 = (const float*)d_in[9];  const float* bq4 = (const float*)d_in[10];
  const float* Wc1 = (const float*)d_in[11]; const float* bc1 = (const float*)d_in[12];
  const float* Wc2 = (const float*)d_in[13]; const float* bc2 = (const float*)d_in[14];
  const float* Wc3 = (const float*)d_in[15]; const float* bc3 = (const float*)d_in[16];
  float* out = (float*)d_out;
  char* ws = (char*)d_ws;

  ushort* x1    = (ushort*)(ws + OFF_X1);
  ushort* x2    = (ushort*)(ws + OFF_X2);
  ushort* aug   = (ushort*)(ws + OFF_AUG);
  ushort* wt1   = (ushort*)(ws + OFF_WT1);
  ushort* wt2   = (ushort*)(ws + OFF_WT2);
  ushort* wt3   = (ushort*)(ws + OFF_WT3);
  float*  qbuf  = (float*) (ws + OFF_Q);
  float*  stats = (float*) (ws + OFF_ST);
  int*    maxb  = (int*)   (ws + OFF_MAX);

  init_kernel<<<128, 256, 0, stream>>>(x1, stats, maxb);
  qconv_kernel<<<64, 128, 0, stream>>>(q_vecs, Wq1,bq1, Wq2,bq2, Wq3,bq3, Wq4,bq4, qbuf);
  aug_kernel<<<dim3(1025, 64), 128, 0, stream>>>(trees, qbuf, aug);
  prepw_kernel<<<(512*384 + 255)/256, 256, 0, stream>>>(Wc1, wt1, 512, 128);
  prepw_kernel<<<(256*1536 + 255)/256, 256, 0, stream>>>(Wc2, wt2, 256, 512);
  prepw_kernel<<<(128*768 + 255)/256, 256, 0, stream>>>(Wc3, wt3, 128, 256);

  conv_kernel<128, 4, false><<<2048, 256, 0, stream>>>(aug, wt1, bc1, idxes, x1, stats +   0, nullptr);
  zero2_kernel<<<64, 256, 0, stream>>>(x2);   // aug (aliased with x2) is dead now
  norm_kernel<<<dim3((65600 + 255)/256, 64), 256, 0, stream>>>(x1, stats +   0, 524800.f, 65600);
  conv_kernel<512, 2, false><<<1024, 256, 0, stream>>>(x1,  wt2, bc2, idxes, x2, stats + 128, nullptr);
  norm_kernel<<<dim3((32800 + 255)/256, 64), 256, 0, stream>>>(x2, stats + 128, 262400.f, 32800);
  conv_kernel<256, 1, true ><<<512, 256, 0, stream>>>(x2,  wt3, bc3, idxes, nullptr, stats + 256, maxb);
  final_kernel<<<32, 256, 0, stream>>>(maxb, stats + 256, out);
}

// Round 7
// 259.195 us; speedup vs baseline: 2.0268x; 1.0663x over previous
//
#include <hip/hip_runtime.h>
#include <hip/hip_bf16.h>

typedef __attribute__((ext_vector_type(8))) short short8;
typedef __attribute__((ext_vector_type(4))) float f32x4;

#define EPSV 1e-5f

__device__ __forceinline__ float bf2f(ushort u){
  union { uint i; float f; } x; x.i = ((uint)u) << 16; return x.f;
}
__device__ __forceinline__ ushort f2bf(float f){
  union { float f; uint i; } x; x.f = f;
  uint r = (x.i + 0x7FFFu + ((x.i >> 16) & 1u)) >> 16;
  return (ushort)r;
}

// ---------------- init: zero stats, max accumulators, row 0 of x1 ----------------
__global__ void init_kernel(ushort* x1, float* stats, int* maxbuf){
  int i = blockIdx.x * 256 + threadIdx.x;   // 32768 threads
  if (i < 384)  stats[i] = 0.f;
  if (i < 8192) maxbuf[i] = 0;
  if (i < 32768){ int b = i >> 9, c = i & 511; x1[(size_t)b*1025*512 + c] = 0; }
}

// ---------------- zero node-0 rows of x2 (AFTER aug is dead: aug aliases x2) ----------------
__global__ void zero2_kernel(ushort* x2){
  int i = blockIdx.x * 256 + threadIdx.x;   // 16384 threads
  int b = i >> 8, c = i & 255;
  x2[(size_t)b*1025*256 + c] = 0;
}

// ---------------- q_conv: 4 stacked linears, no activations ----------------
__global__ void qconv_kernel(const float* __restrict__ qv,
    const float* __restrict__ W1, const float* __restrict__ b1,
    const float* __restrict__ W2, const float* __restrict__ b2,
    const float* __restrict__ W3, const float* __restrict__ b3,
    const float* __restrict__ W4, const float* __restrict__ b4,
    float* __restrict__ qout){
  __shared__ float v0[96], h1[64], h2[128], h3[64];
  int b = blockIdx.x, t = threadIdx.x;
  if (t < 95) v0[t] = qv[b*95 + t];
  __syncthreads();
  if (t < 64){ float s = b1[t]; for (int i=0;i<95;i++)  s += v0[i]*W1[i*64 + t];  h1[t]=s; }
  __syncthreads();
  if (t < 128){ float s = b2[t]; for (int i=0;i<64;i++)  s += h1[i]*W2[i*128 + t]; h2[t]=s; }
  __syncthreads();
  if (t < 64){ float s = b3[t]; for (int i=0;i<128;i++) s += h2[i]*W3[i*64 + t];  h3[t]=s; }
  __syncthreads();
  if (t < 32){ float s = b4[t]; for (int i=0;i<64;i++)  s += h3[i]*W4[i*32 + t];  qout[b*32 + t]=s; }
}

// ---------------- build augmented input (B,1025,128) bf16 ----------------
__global__ void aug_kernel(const float* __restrict__ trees, const float* __restrict__ q,
                           ushort* __restrict__ aug){
  int n = blockIdx.x;            // 0..1024
  int b = blockIdx.y;            // 0..63
  int c = threadIdx.x;           // 0..127
  float v = (c < 96) ? trees[((size_t)b*1025 + n)*96 + c] : q[b*32 + (c - 96)];
  aug[(((size_t)b*1025 + n) << 7) + c] = f2bf(v);
}

// ---------------- weight transpose: Wt[o][kp*C+c] = Wc[o][c][kp], bf16 ----------------
__global__ void prepw_kernel(const float* __restrict__ wc, ushort* __restrict__ wt,
                             int O, int C){
  int i = blockIdx.x * 256 + threadIdx.x;
  int total = O * 3 * C;
  if (i >= total) return;
  int o  = i / (3*C);
  int K  = i - o*3*C;
  int kp = K / C;
  int c  = K - kp*C;
  wt[i] = f2bf(wc[(o*C + c)*3 + kp]);
}

// ---------------- gathered conv as MFMA GEMM ----------------
// 128x128 tile, BK=32, reg-staged with 2-DEEP prefetch (two named register
// sets; issue->use distance ~2 chunks hides L2 gather latency).
// LDS: linear [buf][128][32]; 16B-chunk swizzle phys=log^((row>>1)&3) on
// write AND read -> 0 bank conflicts (verified R6).
template<int CIN, int GY, bool DO_MAX>
__global__ __launch_bounds__(256) void conv_kernel(
    const ushort* __restrict__ xin, const ushort* __restrict__ wt,
    const float* __restrict__ bias, const int* __restrict__ idxes,
    ushort* __restrict__ xout, float* __restrict__ stats, int* __restrict__ maxbuf){
  constexpr int K3   = 3 * CIN;
  constexpr int NT   = K3 / 32;          // K-chunks of 32 (always even)
  constexpr int LOG2 = (CIN == 128) ? 7 : (CIN == 256) ? 8 : 9;
  constexpr int COUT = GY * 128;
  constexpr int NWG  = 8 * GY * 64;

  // XCD swizzle (verified FETCH drop): contiguous wu range per XCD.
  const int bid  = blockIdx.x;
  const int wu   = (bid & 7) * (NWG >> 3) + (bid >> 3);
  const int m0   = (wu & 7) * 128;
  const int rest = wu >> 3;
  const int o0   = (rest % GY) * 128;
  const int b    = rest / GY;

  const int t = threadIdx.x;
  const int lane = t & 63, wid = t >> 6;
  const int WM = (wid & 1) * 64, WO = (wid >> 1) * 64;
  const int fr = lane & 15, fg = lane >> 4;
  const int fc = (fg ^ ((fr >> 1) & 3)) * 8;   // swizzled read column (ushorts)

  __shared__ __align__(16) union {
    struct { ushort A[2][128][32]; ushort B[2][128][32]; } s;   // 32 KB
    ushort stage[128][132];                                     // 33.8 KB
  } sh;
  __shared__ int idx_s[384];

  for (int i = t; i < 384; i += 256) idx_s[i] = idxes[b*3072 + m0*3 + i];
  __syncthreads();

  // staging: thread t owns row r=t>>1, half h=t&1 (logical chunks 2h, 2h+1)
  const int r = t >> 1, h = t & 1, sx = (r >> 1) & 3;
  const int p0 = ((2*h)     ^ sx) * 8;
  const int p1 = ((2*h + 1) ^ sx) * 8;
  const int n0 = idx_s[r*3 + 0], n1 = idx_s[r*3 + 1], n2 = idx_s[r*3 + 2];
  const ushort* xb   = xin + (size_t)b * 1025 * CIN;
  const ushort* pA0  = xb + (size_t)n0 * CIN + h*16;
  const ushort* pA1  = xb + (size_t)n1 * CIN + h*16;
  const ushort* pA2  = xb + (size_t)n2 * CIN + h*16;
  const ushort* wrow = wt + (size_t)(o0 + r) * K3 + h*16;

  // two prefetch register sets — named scalars only (no scratch; R5 lesson)
  uint4 a00, a01, b00, b01;   // set 0: even chunks
  uint4 a10, a11, b10, b11;   // set 1: odd chunks

  auto GLOAD0 = [&](int ch){
    const int k0 = ch * 32;
    const int kp = k0 >> LOG2;
    const int c0 = k0 - (kp << LOG2);
    const ushort* sa = ((kp == 0) ? pA0 : (kp == 1) ? pA1 : pA2) + c0;
    a00 = *reinterpret_cast<const uint4*>(sa);
    a01 = *reinterpret_cast<const uint4*>(sa + 8);
    const ushort* sb = wrow + k0;
    b00 = *reinterpret_cast<const uint4*>(sb);
    b01 = *reinterpret_cast<const uint4*>(sb + 8);
  };
  auto GLOAD1 = [&](int ch){
    const int k0 = ch * 32;
    const int kp = k0 >> LOG2;
    const int c0 = k0 - (kp << LOG2);
    const ushort* sa = ((kp == 0) ? pA0 : (kp == 1) ? pA1 : pA2) + c0;
    a10 = *reinterpret_cast<const uint4*>(sa);
    a11 = *reinterpret_cast<const uint4*>(sa + 8);
    const ushort* sb = wrow + k0;
    b10 = *reinterpret_cast<const uint4*>(sb);
    b11 = *reinterpret_cast<const uint4*>(sb + 8);
  };
  auto DSW0 = [&](int bf){
    *reinterpret_cast<uint4*>(&sh.s.A[bf][r][p0]) = a00;
    *reinterpret_cast<uint4*>(&sh.s.A[bf][r][p1]) = a01;
    *reinterpret_cast<uint4*>(&sh.s.B[bf][r][p0]) = b00;
    *reinterpret_cast<uint4*>(&sh.s.B[bf][r][p1]) = b01;
  };
  auto DSW1 = [&](int bf){
    *reinterpret_cast<uint4*>(&sh.s.A[bf][r][p0]) = a10;
    *reinterpret_cast<uint4*>(&sh.s.A[bf][r][p1]) = a11;
    *reinterpret_cast<uint4*>(&sh.s.B[bf][r][p0]) = b10;
    *reinterpret_cast<uint4*>(&sh.s.B[bf][r][p1]) = b11;
  };

  f32x4 acc[4][4] = {};
  auto COMPUTE = [&](int cur){
    short8 af[4], bf4[4];
    #pragma unroll
    for (int i = 0; i < 4; ++i){
      af[i]  = *reinterpret_cast<const short8*>(&sh.s.A[cur][WM + i*16 + fr][fc]);
      bf4[i] = *reinterpret_cast<const short8*>(&sh.s.B[cur][WO + i*16 + fr][fc]);
    }
    __builtin_amdgcn_s_setprio(1);
    #pragma unroll
    for (int mf = 0; mf < 4; ++mf)
      #pragma unroll
      for (int nf = 0; nf < 4; ++nf)
        acc[mf][nf] = __builtin_amdgcn_mfma_f32_16x16x32_bf16(af[mf], bf4[nf], acc[mf][nf], 0, 0, 0);
    __builtin_amdgcn_s_setprio(0);
  };

  // prologue: chunk0 -> LDS buf0, chunk1 -> set1
  GLOAD0(0);
  DSW0(0);
  GLOAD1(1);
  __syncthreads();

  for (int ch = 0; ch < NT; ch += 2){
    // even chunk: set0 free, set1 holds ch+1
    if (ch + 2 < NT) GLOAD0(ch + 2);     // issue 2 ahead
    COMPUTE(0);
    DSW1(1);                             // waits only set1's loads (vmcnt(4))
    __syncthreads();
    // odd chunk: set1 free, set0 holds ch+2
    if (ch + 3 < NT) GLOAD1(ch + 3);
    COMPUTE(1);
    if (ch + 2 < NT){
      DSW0(0);
      __syncthreads();
    }
  }

  // ---- epilogue: bias, stats, optional max, optional store ----
  float bsv[4];
  #pragma unroll
  for (int nf = 0; nf < 4; ++nf) bsv[nf] = bias[o0 + WO + nf*16 + fr];
  float lsum = 0.f, lsq = 0.f;
  float cmax[4] = { -1e30f, -1e30f, -1e30f, -1e30f };
  #pragma unroll
  for (int mf = 0; mf < 4; ++mf)
    #pragma unroll
    for (int nf = 0; nf < 4; ++nf)
      #pragma unroll
      for (int i = 0; i < 4; ++i){
        float v = acc[mf][nf][i] + bsv[nf];
        lsum += v; lsq += v*v;
        if (DO_MAX) cmax[nf] = fmaxf(cmax[nf], v);
        else acc[mf][nf][i] = v;
      }
  #pragma unroll
  for (int off = 1; off < 64; off <<= 1){
    lsum += __shfl_xor(lsum, off);
    lsq  += __shfl_xor(lsq,  off);
  }
  if (lane == 0){
    atomicAdd(&stats[b],      lsum);
    atomicAdd(&stats[64 + b], lsq);
  }
  if (DO_MAX){
    #pragma unroll
    for (int nf = 0; nf < 4; ++nf){
      float v = cmax[nf];
      v = fmaxf(v, __shfl_xor(v, 16));
      v = fmaxf(v, __shfl_xor(v, 32));
      if (lane < 16)
        atomicMax(&maxbuf[b*COUT + o0 + WO + nf*16 + fr], __float_as_int(v));
    }
  } else {
    __syncthreads();   // all waves done with K-buffers; reuse as staging
    #pragma unroll
    for (int mf = 0; mf < 4; ++mf)
      #pragma unroll
      for (int nf = 0; nf < 4; ++nf)
        #pragma unroll
        for (int i = 0; i < 4; ++i)
          sh.stage[WM + mf*16 + fg*4 + i][WO + nf*16 + fr] = f2bf(acc[mf][nf][i]);
    __syncthreads();
    #pragma unroll
    for (int it = 0; it < 16; ++it){
      int row = it*8 + (t >> 5);
      int col = (t & 31) * 4;
      uint2 v = *reinterpret_cast<const uint2*>(&sh.stage[row][col]);
      *reinterpret_cast<uint2*>(xout + ((size_t)(b*1025 + 1 + m0 + row))*COUT + o0 + col) = v;
    }
  }
}

// ---------------- in-place TreeLayerNorm + leaky_relu, bf16x8 vectorized ----------------
__global__ void norm_kernel(ushort* __restrict__ x, const float* __restrict__ st,
                            float cnt, int nvec_per_b){
  int b = blockIdx.y;
  int j = blockIdx.x * 256 + threadIdx.x;
  if (j >= nvec_per_b) return;
  float sum = st[b], sq = st[64 + b];
  float mean = sum / cnt;
  float var  = fmaxf((sq - sum*sum/cnt) / (cnt - 1.f), 0.f);
  float rs   = 1.f / (sqrtf(var) + EPSV);
  ushort* p = x + ((size_t)b * nvec_per_b + j) * 8;
  union { uint4 v; ushort u[8]; } d;
  d.v = *reinterpret_cast<const uint4*>(p);
  #pragma unroll
  for (int k = 0; k < 8; ++k){
    float f = bf2f(d.u[k]);
    f = (f - mean) * rs;
    f = (f >= 0.f) ? f : 0.01f * f;
    d.u[k] = f2bf(f);
  }
  *reinterpret_cast<uint4*>(p) = d.v;
}

// ---------------- final: normalize the per-channel max ----------------
__global__ void final_kernel(const int* __restrict__ maxbuf, const float* __restrict__ st,
                             float* __restrict__ out){
  int i = blockIdx.x * 256 + threadIdx.x;   // 8192
  int b = i >> 7;
  const float cnt = 131200.f;
  float sum = st[b], sq = st[64 + b];
  float mean = sum / cnt;
  float var  = fmaxf((sq - sum*sum/cnt) / (cnt - 1.f), 0.f);
  float rs   = 1.f / (sqrtf(var) + EPSV);
  out[i] = (__int_as_float(maxbuf[i]) - mean) * rs;
}

// ---------------- workspace layout ----------------
static constexpr size_t SZ_X1  = (size_t)64*1025*512*2;   // 67,174,400
static constexpr size_t SZ_X2  = (size_t)64*1025*256*2;   // 33,587,200
static constexpr size_t OFF_X1 = 0;
static constexpr size_t OFF_X2 = OFF_X1 + SZ_X1;
static constexpr size_t OFF_AUG = OFF_X2;                 // alias: aug dead after conv1
static constexpr size_t OFF_WT1 = OFF_X2 + SZ_X2;
static constexpr size_t OFF_WT2 = OFF_WT1 + (size_t)512*384*2;
static constexpr size_t OFF_WT3 = OFF_WT2 + (size_t)256*1536*2;
static constexpr size_t OFF_Q   = OFF_WT3 + (size_t)128*768*2;
static constexpr size_t OFF_ST  = OFF_Q + (size_t)64*32*4;
static constexpr size_t OFF_MAX = OFF_ST + (size_t)384*4;

extern "C" void kernel_launch(void* const* d_in, const int* in_sizes, int n_in,
                              void* d_out, int out_size, void* d_ws, size_t ws_size,
                              hipStream_t stream){
  const float* q_vecs = (const float*)d_in[0];
  const float* trees  = (const float*)d_in[1];
  const int*   idxes  = (const int*)  d_in[2];
  const float* Wq1 = (const float*)d_in[3];  const float* bq1 = (const float*)d_in[4];
  const float* Wq2 = (const float*)d_in[5];  const float* bq2 = (const float*)d_in[6];
  const float* Wq3 = (const float*)d_in[7];  const float* bq3 = (const float*)d_in[8];
  const float* Wq4 = (const float*)d_in[9];  const float* bq4 = (const float*)d_in[10];
  const float* Wc1 = (const float*)d_in[11]; const float* bc1 = (const float*)d_in[12];
  const float* Wc2 = (const float*)d_in[13]; const float* bc2 = (const float*)d_in[14];
  const float* Wc3 = (const float*)d_in[15]; const float* bc3 = (const float*)d_in[16];
  float* out = (float*)d_out;
  char* ws = (char*)d_ws;

  ushort* x1    = (ushort*)(ws + OFF_X1);
  ushort* x2    = (ushort*)(ws + OFF_X2);
  ushort* aug   = (ushort*)(ws + OFF_AUG);
  ushort* wt1   = (ushort*)(ws + OFF_WT1);
  ushort* wt2   = (ushort*)(ws + OFF_WT2);
  ushort* wt3   = (ushort*)(ws + OFF_WT3);
  float*  qbuf  = (float*) (ws + OFF_Q);
  float*  stats = (float*) (ws + OFF_ST);
  int*    maxb  = (int*)   (ws + OFF_MAX);

  init_kernel<<<128, 256, 0, stream>>>(x1, stats, maxb);
  qconv_kernel<<<64, 128, 0, stream>>>(q_vecs, Wq1,bq1, Wq2,bq2, Wq3,bq3, Wq4,bq4, qbuf);
  aug_kernel<<<dim3(1025, 64), 128, 0, stream>>>(trees, qbuf, aug);
  prepw_kernel<<<(512*384 + 255)/256, 256, 0, stream>>>(Wc1, wt1, 512, 128);
  prepw_kernel<<<(256*1536 + 255)/256, 256, 0, stream>>>(Wc2, wt2, 256, 512);
  prepw_kernel<<<(128*768 + 255)/256, 256, 0, stream>>>(Wc3, wt3, 128, 256);

  conv_kernel<128, 4, false><<<2048, 256, 0, stream>>>(aug, wt1, bc1, idxes, x1, stats +   0, nullptr);
  zero2_kernel<<<64, 256, 0, stream>>>(x2);   // aug (aliased with x2) is dead now
  norm_kernel<<<dim3((65600 + 255)/256, 64), 256, 0, stream>>>(x1, stats +   0, 524800.f, 65600);
  conv_kernel<512, 2, false><<<1024, 256, 0, stream>>>(x1,  wt2, bc2, idxes, x2, stats + 128, nullptr);
  norm_kernel<<<dim3((32800 + 255)/256, 64), 256, 0, stream>>>(x2, stats + 128, 262400.f, 32800);
  conv_kernel<256, 1, true ><<<512, 256, 0, stream>>>(x2,  wt3, bc3, idxes, nullptr, stats + 256, maxb);
  final_kernel<<<32, 256, 0, stream>>>(maxb, stats + 256, out);
}